// Round 1
// baseline (489.847 us; speedup 1.0000x reference)
//
#include <hip/hip_runtime.h>
#include <hip/hip_bf16.h>
#include <stdint.h>

// Problem constants (IMAGE_SIZES is a compile-time constant in the reference)
#define K_DIM 4096          // D * MERGE^2
#define N_DIM 1024          // D
#define M_TOT 11955         // total merged blocks

// Per-image tables: h = H/14, w = W/14; wm = w/2
// imgs: (110,88) (80,110) (64,90) (110,110) (90,64) (52,110)
__constant__ int c_wm[6]     = {44, 55, 45, 55, 32, 55};
__constant__ int c_w[6]      = {88, 110, 90, 110, 64, 110};
__constant__ int c_tokoff[6] = {0, 9680, 18480, 24240, 36340, 42100};
__constant__ int c_blkoff[6] = {0, 2420, 4620, 6060, 9085, 10525};

typedef __attribute__((ext_vector_type(8))) short bf16x8;
typedef __attribute__((ext_vector_type(4))) float f32x4;

// ---------------------------------------------------------------------------
// Pass 1a: gather (2x2 merge, channel-major (d,kh,kw)) + fp32->bf16 convert.
// One block per merged row r. merged[r, k] with k = d*4 + kh*2 + kw.
// Each thread produces 16B chunks of the output row: chunk c covers
// k = 8c..8c+7 => d in {2c, 2c+1}, all (kh,kw). Needs float2 from each of the
// 4 source tokens at feature offset 2c. All loads/stores coalesced.
// ---------------------------------------------------------------------------
__global__ __launch_bounds__(256) void merge_cvt(
    const float* __restrict__ feat, __hip_bfloat16* __restrict__ merged)
{
    const int r = blockIdx.x;
    int img = 0;
#pragma unroll
    for (int t = 1; t < 6; ++t)
        if (r >= c_blkoff[t]) img = t;
    const int bi = r - c_blkoff[img];
    const int wm = c_wm[img];
    const int i = bi / wm;
    const int j = bi - i * wm;
    const int w = c_w[img];

    const size_t base00 = ((size_t)c_tokoff[img] + (size_t)(2 * i) * w + 2 * j) * N_DIM;
    const size_t base01 = base00 + N_DIM;            // kw = 1
    const size_t base10 = base00 + (size_t)w * N_DIM; // kh = 1
    const size_t base11 = base10 + N_DIM;

    __hip_bfloat16* outrow = merged + (size_t)r * K_DIM;

    for (int c = threadIdx.x; c < K_DIM / 8; c += 256) {
        const int d2 = 2 * c;
        float2 f00 = *(const float2*)(feat + base00 + d2);
        float2 f01 = *(const float2*)(feat + base01 + d2);
        float2 f10 = *(const float2*)(feat + base10 + d2);
        float2 f11 = *(const float2*)(feat + base11 + d2);
        union { __hip_bfloat16 h[8]; uint4 u; } pk;
        pk.h[0] = __float2bfloat16(f00.x);
        pk.h[1] = __float2bfloat16(f01.x);
        pk.h[2] = __float2bfloat16(f10.x);
        pk.h[3] = __float2bfloat16(f11.x);
        pk.h[4] = __float2bfloat16(f00.y);
        pk.h[5] = __float2bfloat16(f01.y);
        pk.h[6] = __float2bfloat16(f10.y);
        pk.h[7] = __float2bfloat16(f11.y);
        *(uint4*)(outrow + 8 * c) = pk.u;
    }
}

// ---------------------------------------------------------------------------
// Pass 1b: weight fp32 -> bf16 (1024 x 4096, row-major, K contiguous)
// ---------------------------------------------------------------------------
__global__ __launch_bounds__(256) void wcvt(
    const float* __restrict__ src, __hip_bfloat16* __restrict__ dst)
{
    const int idx = blockIdx.x * 256 + threadIdx.x; // one 8-elem chunk each
    const float4* s = (const float4*)src + (size_t)idx * 2;
    float4 a = s[0], b = s[1];
    union { __hip_bfloat16 h[8]; uint4 u; } pk;
    pk.h[0] = __float2bfloat16(a.x);
    pk.h[1] = __float2bfloat16(a.y);
    pk.h[2] = __float2bfloat16(a.z);
    pk.h[3] = __float2bfloat16(a.w);
    pk.h[4] = __float2bfloat16(b.x);
    pk.h[5] = __float2bfloat16(b.y);
    pk.h[6] = __float2bfloat16(b.z);
    pk.h[7] = __float2bfloat16(b.w);
    *((uint4*)dst + idx) = pk.u;
}

// ---------------------------------------------------------------------------
// Pass 2: bf16 GEMM, C[m,n] = sum_k A[m,k] * W[n,k]  (B^T layout, m97 style)
// 128x128 tile, BK=32, 256 threads (4 waves, 2x2 of 64x64), 16x16x32 MFMA,
// global_load_lds width-16 staging (LDS dst = wave base + lane*16).
// ---------------------------------------------------------------------------
#define BM 128
#define BN 128
#define BK 32

__global__ __launch_bounds__(256) void gemm_bt(
    const __hip_bfloat16* __restrict__ A,
    const __hip_bfloat16* __restrict__ B,
    float* __restrict__ C)
{
    __shared__ __align__(16) __hip_bfloat16 lA[BM * BK]; // 8 KB
    __shared__ __align__(16) __hip_bfloat16 lB[BN * BK]; // 8 KB

    const int tid = threadIdx.x;
    const int lane = tid & 63;
    const int wave = tid >> 6;
    const int m0 = blockIdx.y * BM;
    const int n0 = blockIdx.x * BN;
    const int wm = (wave >> 1) * 64;
    const int wn = (wave & 1) * 64;
    const int al = lane & 15;
    const int q = lane >> 4;

    // staging: chunk c covers LDS elements [8c, 8c+8) = row c>>2, k-part c&3
    const int r0 = tid >> 2;            // rows 0..63 (second chunk: +64)
    const int kp = (tid & 3) * 8;       // k element offset within tile

    int ga0 = m0 + r0;       if (ga0 > M_TOT - 1) ga0 = M_TOT - 1;
    int ga1 = m0 + r0 + 64;  if (ga1 > M_TOT - 1) ga1 = M_TOT - 1;
    const __hip_bfloat16* gA0 = A + (size_t)ga0 * K_DIM + kp;
    const __hip_bfloat16* gA1 = A + (size_t)ga1 * K_DIM + kp;
    const __hip_bfloat16* gB0 = B + (size_t)(n0 + r0) * K_DIM + kp;
    const __hip_bfloat16* gB1 = B + (size_t)(n0 + r0 + 64) * K_DIM + kp;

    __hip_bfloat16* lA0 = lA + tid * 8;
    __hip_bfloat16* lA1 = lA + (tid + 256) * 8;
    __hip_bfloat16* lB0 = lB + tid * 8;
    __hip_bfloat16* lB1 = lB + (tid + 256) * 8;

    f32x4 acc[4][4];
#pragma unroll
    for (int i = 0; i < 4; ++i)
#pragma unroll
        for (int j = 0; j < 4; ++j)
            acc[i][j] = (f32x4){0.f, 0.f, 0.f, 0.f};

    for (int kt = 0; kt < K_DIM; kt += BK) {
        __builtin_amdgcn_global_load_lds(
            (const __attribute__((address_space(1))) void*)(gA0 + kt),
            (__attribute__((address_space(3))) void*)lA0, 16, 0, 0);
        __builtin_amdgcn_global_load_lds(
            (const __attribute__((address_space(1))) void*)(gA1 + kt),
            (__attribute__((address_space(3))) void*)lA1, 16, 0, 0);
        __builtin_amdgcn_global_load_lds(
            (const __attribute__((address_space(1))) void*)(gB0 + kt),
            (__attribute__((address_space(3))) void*)lB0, 16, 0, 0);
        __builtin_amdgcn_global_load_lds(
            (const __attribute__((address_space(1))) void*)(gB1 + kt),
            (__attribute__((address_space(3))) void*)lB1, 16, 0, 0);
        __syncthreads();

        bf16x8 af[4], bfr[4];
#pragma unroll
        for (int mi = 0; mi < 4; ++mi)
            af[mi] = *(const bf16x8*)(lA + (wm + mi * 16 + al) * BK + q * 8);
#pragma unroll
        for (int ni = 0; ni < 4; ++ni)
            bfr[ni] = *(const bf16x8*)(lB + (wn + ni * 16 + al) * BK + q * 8);

#pragma unroll
        for (int mi = 0; mi < 4; ++mi)
#pragma unroll
            for (int ni = 0; ni < 4; ++ni)
                acc[mi][ni] = __builtin_amdgcn_mfma_f32_16x16x32_bf16(
                    af[mi], bfr[ni], acc[mi][ni], 0, 0, 0);
        __syncthreads();
    }

    // C/D layout: col = lane&15, row = (lane>>4)*4 + reg
#pragma unroll
    for (int mi = 0; mi < 4; ++mi) {
        const int row = m0 + wm + mi * 16 + q * 4;
#pragma unroll
        for (int ni = 0; ni < 4; ++ni) {
            const int col = n0 + wn + ni * 16 + al;
            float* cp = C + (size_t)row * N_DIM + col;
#pragma unroll
            for (int rg = 0; rg < 4; ++rg) {
                if (row + rg < M_TOT) cp[(size_t)rg * N_DIM] = acc[mi][ni][rg];
            }
        }
    }
}

extern "C" void kernel_launch(void* const* d_in, const int* in_sizes, int n_in,
                              void* d_out, int out_size, void* d_ws, size_t ws_size,
                              hipStream_t stream)
{
    const float* feat = (const float*)d_in[0];
    const float* wgt  = (const float*)d_in[1];
    float* out = (float*)d_out;

    __hip_bfloat16* merged = (__hip_bfloat16*)d_ws;                     // 11955*4096*2 B
    __hip_bfloat16* wbf = (__hip_bfloat16*)((char*)d_ws +
                                            (size_t)M_TOT * K_DIM * 2); // 8 MB

    merge_cvt<<<M_TOT, 256, 0, stream>>>(feat, merged);
    wcvt<<<(N_DIM * K_DIM / 8) / 256, 256, 0, stream>>>(wgt, wbf);

    dim3 grid(N_DIM / BN, (M_TOT + BM - 1) / BM);
    gemm_bt<<<grid, 256, 0, stream>>>(merged, wbf, out);
}